// Round 1
// 198.989 us; speedup vs baseline: 1.1052x; 1.1052x over previous
//
#include <hip/hip_runtime.h>
#include <hip/hip_bf16.h>
#include <stdint.h>

// VQ: x [N=131072, D=64] fp32, E [D=64, K=1024] fp32.
// R6: restructure vq_screen — (1) single MFMA accumulator chain per rowset
// (C-init = e_sq, 6 chained MFMAs: hh+hh+hl+hl+lh+lh) kills 16 accvgpr moves
// + 8 adds per tile; (2) each wave handles 2 rowsets (32 rows, 128 rows/block,
// grid 1024) so per-tile compute (~250 cyc) covers the 1-deep B-prefetch L2
// latency and B-table L2 traffic halves. Screen math identical to R5
// (3 bf16 product terms, fp32 accum, err ~1.5e-4 << TAU=1e-3).
// Verified facts used: A[m=lane&15][k=(lane>>4)*8+j] (m89/m91/m120),
// C/D col=lane&15 row=(lane>>4)*4+reg (m89/m91), frag types short8/float4.

typedef unsigned long long u64;
typedef short short8 __attribute__((ext_vector_type(8)));
typedef float f32x4 __attribute__((ext_vector_type(4)));

constexpr int D = 64;
constexpr int K = 1024;
constexpr int XS = 72;           // LDS row stride in bf16 elems (144 B, 16B-aligned frags)
constexpr int LCAP = 32768;      // refine-list capacity (cap, never near-reached)
constexpr float TAU = 1e-3f;

__device__ __forceinline__ unsigned short bf16_rne(float v) {
    uint32_t u = __float_as_uint(v);
    uint32_t r = u + 0x7FFFu + ((u >> 16) & 1u);
    return (unsigned short)(r >> 16);
}
__device__ __forceinline__ float bf16_f(unsigned short h) {
    return __uint_as_float(((uint32_t)h) << 16);
}
// monotone fp32 -> u32 map (min preserved) — R3-proven
__device__ __forceinline__ uint32_t fmap(float v) {
    uint32_t u = __float_as_uint(v);
    return (u & 0x80000000u) ? ~u : (u | 0x80000000u);
}
__device__ __forceinline__ float funmap(uint32_t m) {
    uint32_t u = (m & 0x80000000u) ? (m ^ 0x80000000u) : ~m;
    return __uint_as_float(u);
}
__device__ __forceinline__ void top2_merge(u64& b, u64& s, u64 ob, u64 os) {
    if (ob < b) { s = (b < os) ? b : os; b = ob; }
    else        { s = (ob < s) ? ob : s; }
}
__device__ __forceinline__ u64 shfl_xor_u64(u64 v, int m) {
    uint32_t lo = (uint32_t)v, hi = (uint32_t)(v >> 32);
    lo = (uint32_t)__shfl_xor((int)lo, m, 64);
    hi = (uint32_t)__shfl_xor((int)hi, m, 64);
    return ((u64)hi << 32) | lo;
}
__device__ __forceinline__ double shfl_xor_f64(double v, int m) {
    int lo = __double2loint(v), hi = __double2hiint(v);
    lo = __shfl_xor(lo, m, 64);
    hi = __shfl_xor(hi, m, 64);
    return __hiloint2double(hi, lo);
}

// ---- prep: e_sq (f64/f32), ET[k][d] gather table, Bhi/Blo fragment-linear
//      bf16 tables of -2E (hi + residual lo). grid 256 x 256. ----
__global__ __launch_bounds__(256) void vq_prep(const float* __restrict__ E,
                                               double* __restrict__ e_sq64,
                                               float* __restrict__ e_sq32,
                                               float* __restrict__ ET,
                                               unsigned short* __restrict__ Bhi,
                                               unsigned short* __restrict__ Blo,
                                               int* __restrict__ count) {
    int tid = blockIdx.x * 256 + threadIdx.x;        // 0..65535
    if (tid == 0) *count = 0;
    if (tid < K) {
        int k = tid;
        double s = 0.0;
        for (int d = 0; d < D; ++d) {
            float v = E[d * K + k];
            s = fma((double)v, (double)v, s);
            ET[k * D + d] = v;
        }
        e_sq64[k] = s;
        e_sq32[k] = (float)s;
    }
    // table entry: frag f = t*2+c (t=tile 0..63, c=k-chunk 0..1), lane l, slot j
    //   value = -2*E[d][code], d = 32c + 8*(l>>4) + j, code = 16t + (l&15)
    {
        int j = tid & 7;
        int l = (tid >> 3) & 63;
        int f = tid >> 9;            // 0..127
        int c = f & 1;
        int t = f >> 1;
        int d = 32 * c + 8 * (l >> 4) + j;
        int code = 16 * t + (l & 15);
        float v = -2.0f * E[d * K + code];
        unsigned short h = bf16_rne(v);
        Bhi[tid] = h;
        Blo[tid] = bf16_rne(v - bf16_f(h));
    }
}

// ---- screen: block = 128 rows (4 waves x 32), all 1024 codes ----
__global__ __launch_bounds__(256, 3) void vq_screen(
    const float* __restrict__ x,
    const short8* __restrict__ Bh, const short8* __restrict__ Bl,
    const float* __restrict__ e_sq32, const float* __restrict__ ET,
    float* __restrict__ out, int* __restrict__ count, int* __restrict__ list) {
    __shared__ unsigned short xhi[128 * XS];   // 18.4 KB
    __shared__ unsigned short xlo[128 * XS];   // 18.4 KB
    __shared__ float esq[K];                   // 4 KB
    __shared__ int bk[128];

    const int t0 = threadIdx.x;
    const int base = blockIdx.x * 128;

    // stage e_sq
    #pragma unroll
    for (int i = 0; i < 4; ++i) esq[i * 256 + t0] = e_sq32[i * 256 + t0];

    // stage x, split into bf16 hi + lo (thread owns 32 floats = half a row)
    {
        int row = t0 >> 1, seg = t0 & 1;
        const float4* xp = (const float4*)(x + (size_t)(base + row) * D + seg * 32);
        short8 H[4], L[4];
        #pragma unroll
        for (int q = 0; q < 8; ++q) {
            float4 v = xp[q];
            float vv[4] = {v.x, v.y, v.z, v.w};
            #pragma unroll
            for (int e = 0; e < 4; ++e) {
                unsigned short h = bf16_rne(vv[e]);
                unsigned short lo = bf16_rne(vv[e] - bf16_f(h));
                int p = q * 4 + e;               // compile-time in unrolled loop
                H[p >> 3][p & 7] = (short)h;
                L[p >> 3][p & 7] = (short)lo;
            }
        }
        int off = row * XS + seg * 32;
        #pragma unroll
        for (int q = 0; q < 4; ++q) {
            *(short8*)&xhi[off + q * 8] = H[q];
            *(short8*)&xlo[off + q * 8] = L[q];
        }
    }
    __syncthreads();

    const int wid = t0 >> 6, l = t0 & 63;
    const int col = l & 15, quad = l >> 4;

    // A fragments for 2 rowsets (verified layout: m = lane&15, k = quad*8 + j)
    const int ar0 = wid * 32 + col;
    const int ar1 = ar0 + 16;
    short8 Ah0a = *(const short8*)&xhi[ar0 * XS + quad * 8];
    short8 Ah1a = *(const short8*)&xhi[ar0 * XS + 32 + quad * 8];
    short8 Al0a = *(const short8*)&xlo[ar0 * XS + quad * 8];
    short8 Al1a = *(const short8*)&xlo[ar0 * XS + 32 + quad * 8];
    short8 Ah0b = *(const short8*)&xhi[ar1 * XS + quad * 8];
    short8 Ah1b = *(const short8*)&xhi[ar1 * XS + 32 + quad * 8];
    short8 Al0b = *(const short8*)&xlo[ar1 * XS + quad * 8];
    short8 Al1b = *(const short8*)&xlo[ar1 * XS + 32 + quad * 8];

    float besta[4], seca[4], bestb[4], secb[4];
    int bidxa[4], bidxb[4];
    #pragma unroll
    for (int r = 0; r < 4; ++r) {
        besta[r] = 3.4e38f; seca[r] = 3.4e38f; bidxa[r] = 0;
        bestb[r] = 3.4e38f; secb[r] = 3.4e38f; bidxb[r] = 0;
    }

    short8 bh0 = Bh[l], bh1 = Bh[64 + l];
    short8 bl0 = Bl[l], bl1 = Bl[64 + l];

    for (int t = 0; t < 64; ++t) {
        // prefetch next tile's B frags (t=63 wraps to 0 — valid memory, unused)
        int fb = ((t + 1) & 63) * 128 + l;
        short8 nh0 = Bh[fb], nh1 = Bh[fb + 64];
        short8 nl0 = Bl[fb], nl1 = Bl[fb + 64];

        float esv = esq[t * 16 + col];           // same addr across quads -> broadcast
        f32x4 Ca = {esv, esv, esv, esv};
        f32x4 Cb = {esv, esv, esv, esv};
        // single chain per rowset; a/b chains independent -> ILP for the pipe
        Ca = __builtin_amdgcn_mfma_f32_16x16x32_bf16(Ah0a, bh0, Ca, 0, 0, 0);
        Cb = __builtin_amdgcn_mfma_f32_16x16x32_bf16(Ah0b, bh0, Cb, 0, 0, 0);
        Ca = __builtin_amdgcn_mfma_f32_16x16x32_bf16(Ah1a, bh1, Ca, 0, 0, 0);
        Cb = __builtin_amdgcn_mfma_f32_16x16x32_bf16(Ah1b, bh1, Cb, 0, 0, 0);
        Ca = __builtin_amdgcn_mfma_f32_16x16x32_bf16(Ah0a, bl0, Ca, 0, 0, 0);
        Cb = __builtin_amdgcn_mfma_f32_16x16x32_bf16(Ah0b, bl0, Cb, 0, 0, 0);
        Ca = __builtin_amdgcn_mfma_f32_16x16x32_bf16(Ah1a, bl1, Ca, 0, 0, 0);
        Cb = __builtin_amdgcn_mfma_f32_16x16x32_bf16(Ah1b, bl1, Cb, 0, 0, 0);
        Ca = __builtin_amdgcn_mfma_f32_16x16x32_bf16(Al0a, bh0, Ca, 0, 0, 0);
        Cb = __builtin_amdgcn_mfma_f32_16x16x32_bf16(Al0b, bh0, Cb, 0, 0, 0);
        Ca = __builtin_amdgcn_mfma_f32_16x16x32_bf16(Al1a, bh1, Ca, 0, 0, 0);
        Cb = __builtin_amdgcn_mfma_f32_16x16x32_bf16(Al1b, bh1, Cb, 0, 0, 0);

        int tc = t * 16;
        #pragma unroll
        for (int r = 0; r < 4; ++r) {
            float va = Ca[r];
            bool lta = va < besta[r];
            float mxa = fmaxf(va, besta[r]);
            besta[r] = fminf(va, besta[r]);
            seca[r]  = fminf(seca[r], mxa);
            bidxa[r] = lta ? tc : bidxa[r];
            float vb = Cb[r];
            bool ltb = vb < bestb[r];
            float mxb = fmaxf(vb, bestb[r]);
            bestb[r] = fminf(vb, bestb[r]);
            secb[r]  = fminf(secb[r], mxb);
            bidxb[r] = ltb ? tc : bidxb[r];
        }
        bh0 = nh0; bh1 = nh1; bl0 = nl0; bl1 = nl1;
    }

    // per-register reduce across the 16 col-lanes (masks 1..8 preserve quad)
    #pragma unroll
    for (int r = 0; r < 4; ++r) {
        {   // rowset a
            u64 b = ((u64)fmap(besta[r]) << 32) | (uint32_t)(bidxa[r] + col);
            u64 s = ((u64)fmap(seca[r]) << 32) | 0xFFFFFFFFu;
            #pragma unroll
            for (int m = 8; m >= 1; m >>= 1) {
                u64 ob = shfl_xor_u64(b, m);
                u64 os = shfl_xor_u64(s, m);
                top2_merge(b, s, ob, os);
            }
            if (col == 0) {
                int rowL = wid * 32 + quad * 4 + r;       // verified C row map
                bk[rowL] = (int)(uint32_t)(b & 0xFFFFFFFFu);
                float vb = funmap((uint32_t)(b >> 32));
                float vs = funmap((uint32_t)(s >> 32));
                if (vs - vb < TAU) {
                    int idx = atomicAdd(count, 1);
                    if (idx < LCAP) list[idx] = base + rowL;
                }
            }
        }
        {   // rowset b
            u64 b = ((u64)fmap(bestb[r]) << 32) | (uint32_t)(bidxb[r] + col);
            u64 s = ((u64)fmap(secb[r]) << 32) | 0xFFFFFFFFu;
            #pragma unroll
            for (int m = 8; m >= 1; m >>= 1) {
                u64 ob = shfl_xor_u64(b, m);
                u64 os = shfl_xor_u64(s, m);
                top2_merge(b, s, ob, os);
            }
            if (col == 0) {
                int rowL = wid * 32 + 16 + quad * 4 + r;
                bk[rowL] = (int)(uint32_t)(b & 0xFFFFFFFFu);
                float vb = funmap((uint32_t)(b >> 32));
                float vs = funmap((uint32_t)(s >> 32));
                if (vs - vb < TAU) {
                    int idx = atomicAdd(count, 1);
                    if (idx < LCAP) list[idx] = base + rowL;
                }
            }
        }
    }
    __syncthreads();

    // gather: thread t0 copies 128 B of its row from ET
    {
        int row = t0 >> 1, seg = t0 & 1;
        const float4* ep = (const float4*)(ET + (size_t)bk[row] * D + seg * 32);
        float4* op = (float4*)(out + (size_t)(base + row) * D + seg * 32);
        #pragma unroll
        for (int q = 0; q < 8; ++q) op[q] = ep[q];
    }
}

// ---- refine: exact fp64 argmin for flagged rows (R2/R3-proven) ----
__global__ __launch_bounds__(256) void vq_refine(
    const float* __restrict__ x, const float* __restrict__ E,
    const double* __restrict__ e_sq64, const float* __restrict__ ET,
    float* __restrict__ out, const int* __restrict__ count,
    const int* __restrict__ list) {
    __shared__ double xs[D];
    __shared__ double wbv[4];
    __shared__ int wbk[4];
    __shared__ int bks;
    const int t = threadIdx.x;
    int n = *count;
    if (n > LCAP) n = LCAP;
    for (int i = blockIdx.x; i < n; i += gridDim.x) {
        int row = list[i];
        if (t < D) xs[t] = (double)x[(size_t)row * D + t];
        __syncthreads();
        double best = 1.0e300; int bestk = 0;
        #pragma unroll
        for (int j = 0; j < 4; ++j) {
            int k = t * 4 + j;
            double a = 0.0;
            for (int d = 0; d < D; ++d)
                a = fma(xs[d], (double)E[d * K + k], a);
            double v = fma(-2.0, a, e_sq64[k]);
            if (v < best) { best = v; bestk = k; }
        }
        #pragma unroll
        for (int m = 32; m >= 1; m >>= 1) {
            double ov = shfl_xor_f64(best, m);
            int    ok = __shfl_xor(bestk, m, 64);
            if (ov < best || (ov == best && ok < bestk)) { best = ov; bestk = ok; }
        }
        if ((t & 63) == 0) { wbv[t >> 6] = best; wbk[t >> 6] = bestk; }
        __syncthreads();
        if (t == 0) {
            double bv = wbv[0]; int bb = wbk[0];
            for (int w = 1; w < 4; ++w)
                if (wbv[w] < bv || (wbv[w] == bv && wbk[w] < bb)) { bv = wbv[w]; bb = wbk[w]; }
            bks = bb;
        }
        __syncthreads();
        if (t < D) out[(size_t)row * D + t] = ET[(size_t)bks * D + t];
        __syncthreads();
    }
}

extern "C" void kernel_launch(void* const* d_in, const int* in_sizes, int n_in,
                              void* d_out, int out_size, void* d_ws, size_t ws_size,
                              hipStream_t stream) {
    const float* x = (const float*)d_in[0];
    const float* E = (const float*)d_in[1];
    float* out = (float*)d_out;
    int N = in_sizes[0] / D;   // 131072

    // ws: e_sq64 8K | e_sq32 4K | ET 256K | Bhi 128K | Blo 128K | count 16B | list 128K
    char* w = (char*)d_ws;
    double*         e_sq64 = (double*)w;          w += K * sizeof(double);
    float*          e_sq32 = (float*)w;           w += K * sizeof(float);
    float*          ET     = (float*)w;           w += (size_t)K * D * sizeof(float);
    unsigned short* Bhi    = (unsigned short*)w;  w += (size_t)K * D * sizeof(unsigned short);
    unsigned short* Blo    = (unsigned short*)w;  w += (size_t)K * D * sizeof(unsigned short);
    int*            count  = (int*)w;             w += 16;
    int*            list   = (int*)w;

    vq_prep<<<256, 256, 0, stream>>>(E, e_sq64, e_sq32, ET, Bhi, Blo, count);
    vq_screen<<<N / 128, 256, 0, stream>>>(x, (const short8*)Bhi, (const short8*)Blo,
                                           e_sq32, ET, out, count, list);
    vq_refine<<<1024, 256, 0, stream>>>(x, E, e_sq64, ET, out, count, list);
}

// Round 2
// 196.984 us; speedup vs baseline: 1.1164x; 1.0102x over previous
//
#include <hip/hip_runtime.h>
#include <hip/hip_bf16.h>
#include <stdint.h>

// VQ: x [N=131072, D=64] fp32, E [D=64, K=1024] fp32.
// R7: kill the 37 KB xhi/xlo LDS staging. Each lane loads its A-fragment data
// DIRECTLY from global (4 x 32B contiguous slices of an x row; every 64B line
// fully consumed by the wave -> no overfetch) and hi/lo-splits in registers.
// LDS drops 41.5 KB -> 4.6 KB (esq + bk), occupancy becomes VGPR-limited:
// __launch_bounds__(256,4) caps 128 VGPR -> 4 blocks/CU, and grid 1024 = 4
// blocks/CU of work -> full co-residency, no tail. Screen math identical to
// R5/R6 (3 bf16 product terms, fp32 accum, err ~1.5e-4 << TAU=1e-3).
// Verified facts used: A[m=lane&15][k=(lane>>4)*8+j] (m89/m91/m120),
// C/D col=lane&15 row=(lane>>4)*4+reg (m89/m91), frag types short8/float4.

typedef unsigned long long u64;
typedef short short8 __attribute__((ext_vector_type(8)));
typedef float f32x4 __attribute__((ext_vector_type(4)));

constexpr int D = 64;
constexpr int K = 1024;
constexpr int LCAP = 32768;      // refine-list capacity (cap, never near-reached)
constexpr float TAU = 1e-3f;

__device__ __forceinline__ unsigned short bf16_rne(float v) {
    uint32_t u = __float_as_uint(v);
    uint32_t r = u + 0x7FFFu + ((u >> 16) & 1u);
    return (unsigned short)(r >> 16);
}
__device__ __forceinline__ float bf16_f(unsigned short h) {
    return __uint_as_float(((uint32_t)h) << 16);
}
// monotone fp32 -> u32 map (min preserved) — R3-proven
__device__ __forceinline__ uint32_t fmap(float v) {
    uint32_t u = __float_as_uint(v);
    return (u & 0x80000000u) ? ~u : (u | 0x80000000u);
}
__device__ __forceinline__ float funmap(uint32_t m) {
    uint32_t u = (m & 0x80000000u) ? (m ^ 0x80000000u) : ~m;
    return __uint_as_float(u);
}
__device__ __forceinline__ void top2_merge(u64& b, u64& s, u64 ob, u64 os) {
    if (ob < b) { s = (b < os) ? b : os; b = ob; }
    else        { s = (ob < s) ? ob : s; }
}
__device__ __forceinline__ u64 shfl_xor_u64(u64 v, int m) {
    uint32_t lo = (uint32_t)v, hi = (uint32_t)(v >> 32);
    lo = (uint32_t)__shfl_xor((int)lo, m, 64);
    hi = (uint32_t)__shfl_xor((int)hi, m, 64);
    return ((u64)hi << 32) | lo;
}
__device__ __forceinline__ double shfl_xor_f64(double v, int m) {
    int lo = __double2loint(v), hi = __double2hiint(v);
    lo = __shfl_xor(lo, m, 64);
    hi = __shfl_xor(hi, m, 64);
    return __hiloint2double(hi, lo);
}
// 8 fp32 -> bf16 hi + residual-lo fragments (in-register, no LDS transpose)
__device__ __forceinline__ void cvt8(float4 a, float4 b, short8& H, short8& L) {
    float v[8] = {a.x, a.y, a.z, a.w, b.x, b.y, b.z, b.w};
    #pragma unroll
    for (int e = 0; e < 8; ++e) {
        unsigned short h = bf16_rne(v[e]);
        H[e] = (short)h;
        L[e] = (short)bf16_rne(v[e] - bf16_f(h));
    }
}

// ---- prep: e_sq (f64/f32), ET[k][d] gather table, Bhi/Blo fragment-linear
//      bf16 tables of -2E (hi + residual lo). grid 256 x 256. ----
__global__ __launch_bounds__(256) void vq_prep(const float* __restrict__ E,
                                               double* __restrict__ e_sq64,
                                               float* __restrict__ e_sq32,
                                               float* __restrict__ ET,
                                               unsigned short* __restrict__ Bhi,
                                               unsigned short* __restrict__ Blo,
                                               int* __restrict__ count) {
    int tid = blockIdx.x * 256 + threadIdx.x;        // 0..65535
    if (tid == 0) *count = 0;
    if (tid < K) {
        int k = tid;
        double s = 0.0;
        for (int d = 0; d < D; ++d) {
            float v = E[d * K + k];
            s = fma((double)v, (double)v, s);
            ET[k * D + d] = v;
        }
        e_sq64[k] = s;
        e_sq32[k] = (float)s;
    }
    // table entry: frag f = t*2+c (t=tile 0..63, c=k-chunk 0..1), lane l, slot j
    //   value = -2*E[d][code], d = 32c + 8*(l>>4) + j, code = 16t + (l&15)
    {
        int j = tid & 7;
        int l = (tid >> 3) & 63;
        int f = tid >> 9;            // 0..127
        int c = f & 1;
        int t = f >> 1;
        int d = 32 * c + 8 * (l >> 4) + j;
        int code = 16 * t + (l & 15);
        float v = -2.0f * E[d * K + code];
        unsigned short h = bf16_rne(v);
        Bhi[tid] = h;
        Blo[tid] = bf16_rne(v - bf16_f(h));
    }
}

// ---- screen: block = 128 rows (4 waves x 32), all 1024 codes ----
__global__ __launch_bounds__(256, 4) void vq_screen(
    const float* __restrict__ x,
    const short8* __restrict__ Bh, const short8* __restrict__ Bl,
    const float* __restrict__ e_sq32, const float* __restrict__ ET,
    float* __restrict__ out, int* __restrict__ count, int* __restrict__ list) {
    __shared__ float esq[K];                   // 4 KB
    __shared__ int bk[128];                    // 0.5 KB

    const int t0 = threadIdx.x;
    const int base = blockIdx.x * 128;

    // stage e_sq
    #pragma unroll
    for (int i = 0; i < 4; ++i) esq[i * 256 + t0] = e_sq32[i * 256 + t0];

    const int wid = t0 >> 6, l = t0 & 63;
    const int col = l & 15, quad = l >> 4;

    // A fragments for 2 rowsets, loaded DIRECTLY from global in fragment order
    // (verified layout: m = lane&15, k = quad*8 + j, k-chunks at 0 and 32).
    // Lane reads 4 x 32B contiguous slices per rowset; lanes l and l+16 cover
    // the two halves of each 64B line within one instruction -> no overfetch.
    const int gr0 = base + wid * 32 + col;     // rowset a global row
    short8 Ah0a, Ah1a, Al0a, Al1a, Ah0b, Ah1b, Al0b, Al1b;
    {
        const float* xr = x + (size_t)gr0 * D + quad * 8;
        float4 p0 = *(const float4*)(xr);
        float4 p1 = *(const float4*)(xr + 4);
        float4 p2 = *(const float4*)(xr + 32);
        float4 p3 = *(const float4*)(xr + 36);
        const float* xs = xr + 16 * D;         // rowset b
        float4 q0 = *(const float4*)(xs);
        float4 q1 = *(const float4*)(xs + 4);
        float4 q2 = *(const float4*)(xs + 32);
        float4 q3 = *(const float4*)(xs + 36);
        cvt8(p0, p1, Ah0a, Al0a);
        cvt8(p2, p3, Ah1a, Al1a);
        cvt8(q0, q1, Ah0b, Al0b);
        cvt8(q2, q3, Ah1b, Al1b);
    }

    float besta[4], seca[4], bestb[4], secb[4];
    int bidxa[4], bidxb[4];
    #pragma unroll
    for (int r = 0; r < 4; ++r) {
        besta[r] = 3.4e38f; seca[r] = 3.4e38f; bidxa[r] = 0;
        bestb[r] = 3.4e38f; secb[r] = 3.4e38f; bidxb[r] = 0;
    }

    short8 bh0 = Bh[l], bh1 = Bh[64 + l];
    short8 bl0 = Bl[l], bl1 = Bl[64 + l];

    __syncthreads();   // esq ready (placed late: overlaps staging with A loads)

    for (int t = 0; t < 64; ++t) {
        // prefetch next tile's B frags (t=63 wraps to 0 — valid memory, unused)
        int fb = ((t + 1) & 63) * 128 + l;
        short8 nh0 = Bh[fb], nh1 = Bh[fb + 64];
        short8 nl0 = Bl[fb], nl1 = Bl[fb + 64];

        float esv = esq[t * 16 + col];           // same addr across quads -> broadcast
        f32x4 Ca = {esv, esv, esv, esv};
        f32x4 Cb = {esv, esv, esv, esv};
        // single chain per rowset; a/b chains independent -> ILP for the pipe
        Ca = __builtin_amdgcn_mfma_f32_16x16x32_bf16(Ah0a, bh0, Ca, 0, 0, 0);
        Cb = __builtin_amdgcn_mfma_f32_16x16x32_bf16(Ah0b, bh0, Cb, 0, 0, 0);
        Ca = __builtin_amdgcn_mfma_f32_16x16x32_bf16(Ah1a, bh1, Ca, 0, 0, 0);
        Cb = __builtin_amdgcn_mfma_f32_16x16x32_bf16(Ah1b, bh1, Cb, 0, 0, 0);
        Ca = __builtin_amdgcn_mfma_f32_16x16x32_bf16(Ah0a, bl0, Ca, 0, 0, 0);
        Cb = __builtin_amdgcn_mfma_f32_16x16x32_bf16(Ah0b, bl0, Cb, 0, 0, 0);
        Ca = __builtin_amdgcn_mfma_f32_16x16x32_bf16(Ah1a, bl1, Ca, 0, 0, 0);
        Cb = __builtin_amdgcn_mfma_f32_16x16x32_bf16(Ah1b, bl1, Cb, 0, 0, 0);
        Ca = __builtin_amdgcn_mfma_f32_16x16x32_bf16(Al0a, bh0, Ca, 0, 0, 0);
        Cb = __builtin_amdgcn_mfma_f32_16x16x32_bf16(Al0b, bh0, Cb, 0, 0, 0);
        Ca = __builtin_amdgcn_mfma_f32_16x16x32_bf16(Al1a, bh1, Ca, 0, 0, 0);
        Cb = __builtin_amdgcn_mfma_f32_16x16x32_bf16(Al1b, bh1, Cb, 0, 0, 0);

        int tc = t * 16;
        #pragma unroll
        for (int r = 0; r < 4; ++r) {
            float va = Ca[r];
            bool lta = va < besta[r];
            float mxa = fmaxf(va, besta[r]);
            besta[r] = fminf(va, besta[r]);
            seca[r]  = fminf(seca[r], mxa);
            bidxa[r] = lta ? tc : bidxa[r];
            float vb = Cb[r];
            bool ltb = vb < bestb[r];
            float mxb = fmaxf(vb, bestb[r]);
            bestb[r] = fminf(vb, bestb[r]);
            secb[r]  = fminf(secb[r], mxb);
            bidxb[r] = ltb ? tc : bidxb[r];
        }
        bh0 = nh0; bh1 = nh1; bl0 = nl0; bl1 = nl1;
    }

    // per-register reduce across the 16 col-lanes (masks 1..8 preserve quad)
    #pragma unroll
    for (int r = 0; r < 4; ++r) {
        {   // rowset a
            u64 b = ((u64)fmap(besta[r]) << 32) | (uint32_t)(bidxa[r] + col);
            u64 s = ((u64)fmap(seca[r]) << 32) | 0xFFFFFFFFu;
            #pragma unroll
            for (int m = 8; m >= 1; m >>= 1) {
                u64 ob = shfl_xor_u64(b, m);
                u64 os = shfl_xor_u64(s, m);
                top2_merge(b, s, ob, os);
            }
            if (col == 0) {
                int rowL = wid * 32 + quad * 4 + r;       // verified C row map
                bk[rowL] = (int)(uint32_t)(b & 0xFFFFFFFFu);
                float vb = funmap((uint32_t)(b >> 32));
                float vs = funmap((uint32_t)(s >> 32));
                if (vs - vb < TAU) {
                    int idx = atomicAdd(count, 1);
                    if (idx < LCAP) list[idx] = base + rowL;
                }
            }
        }
        {   // rowset b
            u64 b = ((u64)fmap(bestb[r]) << 32) | (uint32_t)(bidxb[r] + col);
            u64 s = ((u64)fmap(secb[r]) << 32) | 0xFFFFFFFFu;
            #pragma unroll
            for (int m = 8; m >= 1; m >>= 1) {
                u64 ob = shfl_xor_u64(b, m);
                u64 os = shfl_xor_u64(s, m);
                top2_merge(b, s, ob, os);
            }
            if (col == 0) {
                int rowL = wid * 32 + 16 + quad * 4 + r;
                bk[rowL] = (int)(uint32_t)(b & 0xFFFFFFFFu);
                float vb = funmap((uint32_t)(b >> 32));
                float vs = funmap((uint32_t)(s >> 32));
                if (vs - vb < TAU) {
                    int idx = atomicAdd(count, 1);
                    if (idx < LCAP) list[idx] = base + rowL;
                }
            }
        }
    }
    __syncthreads();

    // gather: thread t0 copies 128 B of its row from ET
    {
        int row = t0 >> 1, seg = t0 & 1;
        const float4* ep = (const float4*)(ET + (size_t)bk[row] * D + seg * 32);
        float4* op = (float4*)(out + (size_t)(base + row) * D + seg * 32);
        #pragma unroll
        for (int q = 0; q < 8; ++q) op[q] = ep[q];
    }
}

// ---- refine: exact fp64 argmin for flagged rows (R2/R3-proven) ----
__global__ __launch_bounds__(256) void vq_refine(
    const float* __restrict__ x, const float* __restrict__ E,
    const double* __restrict__ e_sq64, const float* __restrict__ ET,
    float* __restrict__ out, const int* __restrict__ count,
    const int* __restrict__ list) {
    __shared__ double xs[D];
    __shared__ double wbv[4];
    __shared__ int wbk[4];
    __shared__ int bks;
    const int t = threadIdx.x;
    int n = *count;
    if (n > LCAP) n = LCAP;
    for (int i = blockIdx.x; i < n; i += gridDim.x) {
        int row = list[i];
        if (t < D) xs[t] = (double)x[(size_t)row * D + t];
        __syncthreads();
        double best = 1.0e300; int bestk = 0;
        #pragma unroll
        for (int j = 0; j < 4; ++j) {
            int k = t * 4 + j;
            double a = 0.0;
            for (int d = 0; d < D; ++d)
                a = fma(xs[d], (double)E[d * K + k], a);
            double v = fma(-2.0, a, e_sq64[k]);
            if (v < best) { best = v; bestk = k; }
        }
        #pragma unroll
        for (int m = 32; m >= 1; m >>= 1) {
            double ov = shfl_xor_f64(best, m);
            int    ok = __shfl_xor(bestk, m, 64);
            if (ov < best || (ov == best && ok < bestk)) { best = ov; bestk = ok; }
        }
        if ((t & 63) == 0) { wbv[t >> 6] = best; wbk[t >> 6] = bestk; }
        __syncthreads();
        if (t == 0) {
            double bv = wbv[0]; int bb = wbk[0];
            for (int w = 1; w < 4; ++w)
                if (wbv[w] < bv || (wbv[w] == bv && wbk[w] < bb)) { bv = wbv[w]; bb = wbk[w]; }
            bks = bb;
        }
        __syncthreads();
        if (t < D) out[(size_t)row * D + t] = ET[(size_t)bks * D + t];
        __syncthreads();
    }
}

extern "C" void kernel_launch(void* const* d_in, const int* in_sizes, int n_in,
                              void* d_out, int out_size, void* d_ws, size_t ws_size,
                              hipStream_t stream) {
    const float* x = (const float*)d_in[0];
    const float* E = (const float*)d_in[1];
    float* out = (float*)d_out;
    int N = in_sizes[0] / D;   // 131072

    // ws: e_sq64 8K | e_sq32 4K | ET 256K | Bhi 128K | Blo 128K | count 16B | list 128K
    char* w = (char*)d_ws;
    double*         e_sq64 = (double*)w;          w += K * sizeof(double);
    float*          e_sq32 = (float*)w;           w += K * sizeof(float);
    float*          ET     = (float*)w;           w += (size_t)K * D * sizeof(float);
    unsigned short* Bhi    = (unsigned short*)w;  w += (size_t)K * D * sizeof(unsigned short);
    unsigned short* Blo    = (unsigned short*)w;  w += (size_t)K * D * sizeof(unsigned short);
    int*            count  = (int*)w;             w += 16;
    int*            list   = (int*)w;

    vq_prep<<<256, 256, 0, stream>>>(E, e_sq64, e_sq32, ET, Bhi, Blo, count);
    vq_screen<<<N / 128, 256, 0, stream>>>(x, (const short8*)Bhi, (const short8*)Blo,
                                           e_sq32, ET, out, count, list);
    vq_refine<<<1024, 256, 0, stream>>>(x, E, e_sq64, ET, out, count, list);
}

// Round 3
// 172.936 us; speedup vs baseline: 1.2717x; 1.1391x over previous
//
#include <hip/hip_runtime.h>
#include <hip/hip_bf16.h>
#include <stdint.h>

// VQ: x [N=131072, D=64] fp32, E [D=64, K=1024] fp32.
// R8: FUSE refine into screen. R7 counters showed vq_refine = 91 us with
// VALUBusy 0.02% / occupancy 0.05%: ~34 flagged rows -> ~34 lone blocks each
// running a latency-serialized chain of 4KB-strided cold E loads (VGPR=256,
// near-serial load-use). Fix: per-block LDS flag list; after the reduce phase
// the whole block re-argmins each flagged row in fp64 using the L2-warm
// row-major ET table (ET[k*D+d] == E[d*K+k] exactly; same fma order, same
// tie-breaks as the proven refine kernel), updating bk[] before the gather.
// vq_refine kernel, global count/list, and their launches are deleted.
// Screen math unchanged from R6/R7 (3 bf16 product terms, fp32 accum,
// err ~1.5e-4 << TAU=1e-3).
// Verified facts used: A[m=lane&15][k=(lane>>4)*8+j] (m89/m91/m120),
// C/D col=lane&15 row=(lane>>4)*4+reg (m89/m91), frag types short8/float4.

typedef unsigned long long u64;
typedef short short8 __attribute__((ext_vector_type(8)));
typedef float f32x4 __attribute__((ext_vector_type(4)));

constexpr int D = 64;
constexpr int K = 1024;
constexpr float TAU = 1e-3f;

__device__ __forceinline__ unsigned short bf16_rne(float v) {
    uint32_t u = __float_as_uint(v);
    uint32_t r = u + 0x7FFFu + ((u >> 16) & 1u);
    return (unsigned short)(r >> 16);
}
__device__ __forceinline__ float bf16_f(unsigned short h) {
    return __uint_as_float(((uint32_t)h) << 16);
}
// monotone fp32 -> u32 map (min preserved) — R3-proven
__device__ __forceinline__ uint32_t fmap(float v) {
    uint32_t u = __float_as_uint(v);
    return (u & 0x80000000u) ? ~u : (u | 0x80000000u);
}
__device__ __forceinline__ float funmap(uint32_t m) {
    uint32_t u = (m & 0x80000000u) ? (m ^ 0x80000000u) : ~m;
    return __uint_as_float(u);
}
__device__ __forceinline__ void top2_merge(u64& b, u64& s, u64 ob, u64 os) {
    if (ob < b) { s = (b < os) ? b : os; b = ob; }
    else        { s = (ob < s) ? ob : s; }
}
__device__ __forceinline__ u64 shfl_xor_u64(u64 v, int m) {
    uint32_t lo = (uint32_t)v, hi = (uint32_t)(v >> 32);
    lo = (uint32_t)__shfl_xor((int)lo, m, 64);
    hi = (uint32_t)__shfl_xor((int)hi, m, 64);
    return ((u64)hi << 32) | lo;
}
__device__ __forceinline__ double shfl_xor_f64(double v, int m) {
    int lo = __double2loint(v), hi = __double2hiint(v);
    lo = __shfl_xor(lo, m, 64);
    hi = __shfl_xor(hi, m, 64);
    return __hiloint2double(hi, lo);
}
// 8 fp32 -> bf16 hi + residual-lo fragments (in-register, no LDS transpose)
__device__ __forceinline__ void cvt8(float4 a, float4 b, short8& H, short8& L) {
    float v[8] = {a.x, a.y, a.z, a.w, b.x, b.y, b.z, b.w};
    #pragma unroll
    for (int e = 0; e < 8; ++e) {
        unsigned short h = bf16_rne(v[e]);
        H[e] = (short)h;
        L[e] = (short)bf16_rne(v[e] - bf16_f(h));
    }
}

// ---- prep: e_sq (f64/f32), ET[k][d] gather table, Bhi/Blo fragment-linear
//      bf16 tables of -2E (hi + residual lo). grid 256 x 256. ----
__global__ __launch_bounds__(256) void vq_prep(const float* __restrict__ E,
                                               double* __restrict__ e_sq64,
                                               float* __restrict__ e_sq32,
                                               float* __restrict__ ET,
                                               unsigned short* __restrict__ Bhi,
                                               unsigned short* __restrict__ Blo) {
    int tid = blockIdx.x * 256 + threadIdx.x;        // 0..65535
    if (tid < K) {
        int k = tid;
        double s = 0.0;
        for (int d = 0; d < D; ++d) {
            float v = E[d * K + k];
            s = fma((double)v, (double)v, s);
            ET[k * D + d] = v;
        }
        e_sq64[k] = s;
        e_sq32[k] = (float)s;
    }
    // table entry: frag f = t*2+c (t=tile 0..63, c=k-chunk 0..1), lane l, slot j
    //   value = -2*E[d][code], d = 32c + 8*(l>>4) + j, code = 16t + (l&15)
    {
        int j = tid & 7;
        int l = (tid >> 3) & 63;
        int f = tid >> 9;            // 0..127
        int c = f & 1;
        int t = f >> 1;
        int d = 32 * c + 8 * (l >> 4) + j;
        int code = 16 * t + (l & 15);
        float v = -2.0f * E[d * K + code];
        unsigned short h = bf16_rne(v);
        Bhi[tid] = h;
        Blo[tid] = bf16_rne(v - bf16_f(h));
    }
}

// ---- screen + fused exact refine: block = 128 rows (4 waves x 32) ----
__global__ __launch_bounds__(256, 4) void vq_screen(
    const float* __restrict__ x,
    const short8* __restrict__ Bh, const short8* __restrict__ Bl,
    const float* __restrict__ e_sq32, const double* __restrict__ e_sq64,
    const float* __restrict__ ET, float* __restrict__ out) {
    __shared__ float esq[K];                   // 4 KB
    __shared__ int bk[128];                    // 0.5 KB
    __shared__ double xs64[D];                 // 0.5 KB (refine staging)
    __shared__ double wbv[4];
    __shared__ int wbk_s[4];
    __shared__ int flag_list[128];             // 0.5 KB
    __shared__ int flag_n;

    const int t0 = threadIdx.x;
    const int base = blockIdx.x * 128;

    if (t0 == 0) flag_n = 0;

    // stage e_sq
    #pragma unroll
    for (int i = 0; i < 4; ++i) esq[i * 256 + t0] = e_sq32[i * 256 + t0];

    const int wid = t0 >> 6, l = t0 & 63;
    const int col = l & 15, quad = l >> 4;

    // A fragments for 2 rowsets, loaded DIRECTLY from global in fragment order
    // (verified layout: m = lane&15, k = quad*8 + j, k-chunks at 0 and 32).
    const int gr0 = base + wid * 32 + col;     // rowset a global row
    short8 Ah0a, Ah1a, Al0a, Al1a, Ah0b, Ah1b, Al0b, Al1b;
    {
        const float* xr = x + (size_t)gr0 * D + quad * 8;
        float4 p0 = *(const float4*)(xr);
        float4 p1 = *(const float4*)(xr + 4);
        float4 p2 = *(const float4*)(xr + 32);
        float4 p3 = *(const float4*)(xr + 36);
        const float* xs = xr + 16 * D;         // rowset b
        float4 q0 = *(const float4*)(xs);
        float4 q1 = *(const float4*)(xs + 4);
        float4 q2 = *(const float4*)(xs + 32);
        float4 q3 = *(const float4*)(xs + 36);
        cvt8(p0, p1, Ah0a, Al0a);
        cvt8(p2, p3, Ah1a, Al1a);
        cvt8(q0, q1, Ah0b, Al0b);
        cvt8(q2, q3, Ah1b, Al1b);
    }

    float besta[4], seca[4], bestb[4], secb[4];
    int bidxa[4], bidxb[4];
    #pragma unroll
    for (int r = 0; r < 4; ++r) {
        besta[r] = 3.4e38f; seca[r] = 3.4e38f; bidxa[r] = 0;
        bestb[r] = 3.4e38f; secb[r] = 3.4e38f; bidxb[r] = 0;
    }

    short8 bh0 = Bh[l], bh1 = Bh[64 + l];
    short8 bl0 = Bl[l], bl1 = Bl[64 + l];

    __syncthreads();   // esq + flag_n ready

    for (int t = 0; t < 64; ++t) {
        // prefetch next tile's B frags (t=63 wraps to 0 — valid memory, unused)
        int fb = ((t + 1) & 63) * 128 + l;
        short8 nh0 = Bh[fb], nh1 = Bh[fb + 64];
        short8 nl0 = Bl[fb], nl1 = Bl[fb + 64];

        float esv = esq[t * 16 + col];           // same addr across quads -> broadcast
        f32x4 Ca = {esv, esv, esv, esv};
        f32x4 Cb = {esv, esv, esv, esv};
        // single chain per rowset; a/b chains independent -> ILP for the pipe
        Ca = __builtin_amdgcn_mfma_f32_16x16x32_bf16(Ah0a, bh0, Ca, 0, 0, 0);
        Cb = __builtin_amdgcn_mfma_f32_16x16x32_bf16(Ah0b, bh0, Cb, 0, 0, 0);
        Ca = __builtin_amdgcn_mfma_f32_16x16x32_bf16(Ah1a, bh1, Ca, 0, 0, 0);
        Cb = __builtin_amdgcn_mfma_f32_16x16x32_bf16(Ah1b, bh1, Cb, 0, 0, 0);
        Ca = __builtin_amdgcn_mfma_f32_16x16x32_bf16(Ah0a, bl0, Ca, 0, 0, 0);
        Cb = __builtin_amdgcn_mfma_f32_16x16x32_bf16(Ah0b, bl0, Cb, 0, 0, 0);
        Ca = __builtin_amdgcn_mfma_f32_16x16x32_bf16(Ah1a, bl1, Ca, 0, 0, 0);
        Cb = __builtin_amdgcn_mfma_f32_16x16x32_bf16(Ah1b, bl1, Cb, 0, 0, 0);
        Ca = __builtin_amdgcn_mfma_f32_16x16x32_bf16(Al0a, bh0, Ca, 0, 0, 0);
        Cb = __builtin_amdgcn_mfma_f32_16x16x32_bf16(Al0b, bh0, Cb, 0, 0, 0);
        Ca = __builtin_amdgcn_mfma_f32_16x16x32_bf16(Al1a, bh1, Ca, 0, 0, 0);
        Cb = __builtin_amdgcn_mfma_f32_16x16x32_bf16(Al1b, bh1, Cb, 0, 0, 0);

        int tc = t * 16;
        #pragma unroll
        for (int r = 0; r < 4; ++r) {
            float va = Ca[r];
            bool lta = va < besta[r];
            float mxa = fmaxf(va, besta[r]);
            besta[r] = fminf(va, besta[r]);
            seca[r]  = fminf(seca[r], mxa);
            bidxa[r] = lta ? tc : bidxa[r];
            float vb = Cb[r];
            bool ltb = vb < bestb[r];
            float mxb = fmaxf(vb, bestb[r]);
            bestb[r] = fminf(vb, bestb[r]);
            secb[r]  = fminf(secb[r], mxb);
            bidxb[r] = ltb ? tc : bidxb[r];
        }
        bh0 = nh0; bh1 = nh1; bl0 = nl0; bl1 = nl1;
    }

    // per-register reduce across the 16 col-lanes (masks 1..8 preserve quad)
    #pragma unroll
    for (int r = 0; r < 4; ++r) {
        {   // rowset a
            u64 b = ((u64)fmap(besta[r]) << 32) | (uint32_t)(bidxa[r] + col);
            u64 s = ((u64)fmap(seca[r]) << 32) | 0xFFFFFFFFu;
            #pragma unroll
            for (int m = 8; m >= 1; m >>= 1) {
                u64 ob = shfl_xor_u64(b, m);
                u64 os = shfl_xor_u64(s, m);
                top2_merge(b, s, ob, os);
            }
            if (col == 0) {
                int rowL = wid * 32 + quad * 4 + r;       // verified C row map
                bk[rowL] = (int)(uint32_t)(b & 0xFFFFFFFFu);
                float vb = funmap((uint32_t)(b >> 32));
                float vs = funmap((uint32_t)(s >> 32));
                if (vs - vb < TAU) {
                    int idx = atomicAdd(&flag_n, 1);
                    flag_list[idx] = rowL;
                }
            }
        }
        {   // rowset b
            u64 b = ((u64)fmap(bestb[r]) << 32) | (uint32_t)(bidxb[r] + col);
            u64 s = ((u64)fmap(secb[r]) << 32) | 0xFFFFFFFFu;
            #pragma unroll
            for (int m = 8; m >= 1; m >>= 1) {
                u64 ob = shfl_xor_u64(b, m);
                u64 os = shfl_xor_u64(s, m);
                top2_merge(b, s, ob, os);
            }
            if (col == 0) {
                int rowL = wid * 32 + 16 + quad * 4 + r;
                bk[rowL] = (int)(uint32_t)(b & 0xFFFFFFFFu);
                float vb = funmap((uint32_t)(b >> 32));
                float vs = funmap((uint32_t)(s >> 32));
                if (vs - vb < TAU) {
                    int idx = atomicAdd(&flag_n, 1);
                    flag_list[idx] = rowL;
                }
            }
        }
    }
    __syncthreads();

    // fused exact refine for flagged rows (rare: ~0.03 rows/block expected).
    // Identical math + tie-breaks to the proven vq_refine kernel:
    // ET[k*D+d] == E[d*K+k] exactly; fp64 fma over ascending d; v<best with
    // ascending k; wave reduce then cross-wave lowest-k-on-tie merge.
    {
        int nf = flag_n;                         // uniform across block
        for (int f = 0; f < nf; ++f) {
            int rowR = flag_list[f];
            if (t0 < D) xs64[t0] = (double)x[(size_t)(base + rowR) * D + t0];
            __syncthreads();
            double best = 1.0e300; int bestk = 0;
            #pragma unroll
            for (int j = 0; j < 4; ++j) {
                int k = t0 * 4 + j;
                const float* ep = ET + (size_t)k * D;
                double a = 0.0;
                #pragma unroll 4
                for (int d = 0; d < D; ++d)
                    a = fma(xs64[d], (double)ep[d], a);
                double v = fma(-2.0, a, e_sq64[k]);
                if (v < best) { best = v; bestk = k; }
            }
            #pragma unroll
            for (int m = 32; m >= 1; m >>= 1) {
                double ov = shfl_xor_f64(best, m);
                int    ok = __shfl_xor(bestk, m, 64);
                if (ov < best || (ov == best && ok < bestk)) { best = ov; bestk = ok; }
            }
            if ((t0 & 63) == 0) { wbv[t0 >> 6] = best; wbk_s[t0 >> 6] = bestk; }
            __syncthreads();
            if (t0 == 0) {
                double bv = wbv[0]; int bb = wbk_s[0];
                for (int w = 1; w < 4; ++w)
                    if (wbv[w] < bv || (wbv[w] == bv && wbk_s[w] < bb)) { bv = wbv[w]; bb = wbk_s[w]; }
                bk[rowR] = bb;
            }
            __syncthreads();
        }
    }

    // gather: thread t0 copies 128 B of its row from ET
    {
        int row = t0 >> 1, seg = t0 & 1;
        const float4* ep = (const float4*)(ET + (size_t)bk[row] * D + seg * 32);
        float4* op = (float4*)(out + (size_t)(base + row) * D + seg * 32);
        #pragma unroll
        for (int q = 0; q < 8; ++q) op[q] = ep[q];
    }
}

extern "C" void kernel_launch(void* const* d_in, const int* in_sizes, int n_in,
                              void* d_out, int out_size, void* d_ws, size_t ws_size,
                              hipStream_t stream) {
    const float* x = (const float*)d_in[0];
    const float* E = (const float*)d_in[1];
    float* out = (float*)d_out;
    int N = in_sizes[0] / D;   // 131072

    // ws: e_sq64 8K | e_sq32 4K | ET 256K | Bhi 128K | Blo 128K
    char* w = (char*)d_ws;
    double*         e_sq64 = (double*)w;          w += K * sizeof(double);
    float*          e_sq32 = (float*)w;           w += K * sizeof(float);
    float*          ET     = (float*)w;           w += (size_t)K * D * sizeof(float);
    unsigned short* Bhi    = (unsigned short*)w;  w += (size_t)K * D * sizeof(unsigned short);
    unsigned short* Blo    = (unsigned short*)w;  w += (size_t)K * D * sizeof(unsigned short);

    vq_prep<<<256, 256, 0, stream>>>(E, e_sq64, e_sq32, ET, Bhi, Blo);
    vq_screen<<<N / 128, 256, 0, stream>>>(x, (const short8*)Bhi, (const short8*)Blo,
                                           e_sq32, e_sq64, ET, out);
}

// Round 4
// 161.756 us; speedup vs baseline: 1.3596x; 1.0691x over previous
//
#include <hip/hip_runtime.h>
#include <hip/hip_bf16.h>
#include <stdint.h>

// VQ: x [N=131072, D=64] fp32, E [D=64, K=1024] fp32.
// R9: force the B prefetch to actually happen. R8's VGPR=52 proves the
// compiler SANK the next-tile B loads to the bottom of the loop body (a held
// prefetch would cost ~90 VGPR) -> every tile stalls ~300 cyc on vmcnt right
// before the MFMAs (wall ~500 cyc/tile matches the 254k-cyc kernel). Fix:
// __builtin_amdgcn_sched_barrier(0) pinned AFTER the 4 B loads + esq[t+1]
// prefetch and BEFORE the MFMA chain -> loads issue at body top, waitcnt
// becomes a counted vmcnt at the NEXT body's first use (~1 body of slack).
// #pragma unroll 2 removes the 16 v_mov/tile register rotation.
// Everything else identical to R8 (fused fp64 refine, same math/tie-breaks).
// Verified facts used: A[m=lane&15][k=(lane>>4)*8+j] (m89/m91/m120),
// C/D col=lane&15 row=(lane>>4)*4+reg (m89/m91), frag types short8/float4.

typedef unsigned long long u64;
typedef short short8 __attribute__((ext_vector_type(8)));
typedef float f32x4 __attribute__((ext_vector_type(4)));

constexpr int D = 64;
constexpr int K = 1024;
constexpr float TAU = 1e-3f;

__device__ __forceinline__ unsigned short bf16_rne(float v) {
    uint32_t u = __float_as_uint(v);
    uint32_t r = u + 0x7FFFu + ((u >> 16) & 1u);
    return (unsigned short)(r >> 16);
}
__device__ __forceinline__ float bf16_f(unsigned short h) {
    return __uint_as_float(((uint32_t)h) << 16);
}
// monotone fp32 -> u32 map (min preserved) — R3-proven
__device__ __forceinline__ uint32_t fmap(float v) {
    uint32_t u = __float_as_uint(v);
    return (u & 0x80000000u) ? ~u : (u | 0x80000000u);
}
__device__ __forceinline__ float funmap(uint32_t m) {
    uint32_t u = (m & 0x80000000u) ? (m ^ 0x80000000u) : ~m;
    return __uint_as_float(u);
}
__device__ __forceinline__ void top2_merge(u64& b, u64& s, u64 ob, u64 os) {
    if (ob < b) { s = (b < os) ? b : os; b = ob; }
    else        { s = (ob < s) ? ob : s; }
}
__device__ __forceinline__ u64 shfl_xor_u64(u64 v, int m) {
    uint32_t lo = (uint32_t)v, hi = (uint32_t)(v >> 32);
    lo = (uint32_t)__shfl_xor((int)lo, m, 64);
    hi = (uint32_t)__shfl_xor((int)hi, m, 64);
    return ((u64)hi << 32) | lo;
}
__device__ __forceinline__ double shfl_xor_f64(double v, int m) {
    int lo = __double2loint(v), hi = __double2hiint(v);
    lo = __shfl_xor(lo, m, 64);
    hi = __shfl_xor(hi, m, 64);
    return __hiloint2double(hi, lo);
}
// 8 fp32 -> bf16 hi + residual-lo fragments (in-register, no LDS transpose)
__device__ __forceinline__ void cvt8(float4 a, float4 b, short8& H, short8& L) {
    float v[8] = {a.x, a.y, a.z, a.w, b.x, b.y, b.z, b.w};
    #pragma unroll
    for (int e = 0; e < 8; ++e) {
        unsigned short h = bf16_rne(v[e]);
        H[e] = (short)h;
        L[e] = (short)bf16_rne(v[e] - bf16_f(h));
    }
}

// ---- prep: e_sq (f64/f32), ET[k][d] gather table, Bhi/Blo fragment-linear
//      bf16 tables of -2E (hi + residual lo). grid 256 x 256. ----
__global__ __launch_bounds__(256) void vq_prep(const float* __restrict__ E,
                                               double* __restrict__ e_sq64,
                                               float* __restrict__ e_sq32,
                                               float* __restrict__ ET,
                                               unsigned short* __restrict__ Bhi,
                                               unsigned short* __restrict__ Blo) {
    int tid = blockIdx.x * 256 + threadIdx.x;        // 0..65535
    if (tid < K) {
        int k = tid;
        double s = 0.0;
        for (int d = 0; d < D; ++d) {
            float v = E[d * K + k];
            s = fma((double)v, (double)v, s);
            ET[k * D + d] = v;
        }
        e_sq64[k] = s;
        e_sq32[k] = (float)s;
    }
    // table entry: frag f = t*2+c (t=tile 0..63, c=k-chunk 0..1), lane l, slot j
    //   value = -2*E[d][code], d = 32c + 8*(l>>4) + j, code = 16t + (l&15)
    {
        int j = tid & 7;
        int l = (tid >> 3) & 63;
        int f = tid >> 9;            // 0..127
        int c = f & 1;
        int t = f >> 1;
        int d = 32 * c + 8 * (l >> 4) + j;
        int code = 16 * t + (l & 15);
        float v = -2.0f * E[d * K + code];
        unsigned short h = bf16_rne(v);
        Bhi[tid] = h;
        Blo[tid] = bf16_rne(v - bf16_f(h));
    }
}

// ---- screen + fused exact refine: block = 128 rows (4 waves x 32) ----
__global__ __launch_bounds__(256, 4) void vq_screen(
    const float* __restrict__ x,
    const short8* __restrict__ Bh, const short8* __restrict__ Bl,
    const float* __restrict__ e_sq32, const double* __restrict__ e_sq64,
    const float* __restrict__ ET, float* __restrict__ out) {
    __shared__ float esq[K];                   // 4 KB
    __shared__ int bk[128];                    // 0.5 KB
    __shared__ double xs64[D];                 // 0.5 KB (refine staging)
    __shared__ double wbv[4];
    __shared__ int wbk_s[4];
    __shared__ int flag_list[128];             // 0.5 KB
    __shared__ int flag_n;

    const int t0 = threadIdx.x;
    const int base = blockIdx.x * 128;

    if (t0 == 0) flag_n = 0;

    // stage e_sq
    #pragma unroll
    for (int i = 0; i < 4; ++i) esq[i * 256 + t0] = e_sq32[i * 256 + t0];

    const int wid = t0 >> 6, l = t0 & 63;
    const int col = l & 15, quad = l >> 4;

    // A fragments for 2 rowsets, loaded DIRECTLY from global in fragment order
    // (verified layout: m = lane&15, k = quad*8 + j, k-chunks at 0 and 32).
    const int gr0 = base + wid * 32 + col;     // rowset a global row
    short8 Ah0a, Ah1a, Al0a, Al1a, Ah0b, Ah1b, Al0b, Al1b;
    {
        const float* xr = x + (size_t)gr0 * D + quad * 8;
        float4 p0 = *(const float4*)(xr);
        float4 p1 = *(const float4*)(xr + 4);
        float4 p2 = *(const float4*)(xr + 32);
        float4 p3 = *(const float4*)(xr + 36);
        const float* xs = xr + 16 * D;         // rowset b
        float4 q0 = *(const float4*)(xs);
        float4 q1 = *(const float4*)(xs + 4);
        float4 q2 = *(const float4*)(xs + 32);
        float4 q3 = *(const float4*)(xs + 36);
        cvt8(p0, p1, Ah0a, Al0a);
        cvt8(p2, p3, Ah1a, Al1a);
        cvt8(q0, q1, Ah0b, Al0b);
        cvt8(q2, q3, Ah1b, Al1b);
    }

    float besta[4], seca[4], bestb[4], secb[4];
    int bidxa[4], bidxb[4];
    #pragma unroll
    for (int r = 0; r < 4; ++r) {
        besta[r] = 3.4e38f; seca[r] = 3.4e38f; bidxa[r] = 0;
        bestb[r] = 3.4e38f; secb[r] = 3.4e38f; bidxb[r] = 0;
    }

    short8 bh0 = Bh[l], bh1 = Bh[64 + l];
    short8 bl0 = Bl[l], bl1 = Bl[64 + l];

    __syncthreads();   // esq + flag_n ready

    float esv_c = esq[col];                    // tile 0 e_sq value

    #pragma unroll 2
    for (int t = 0; t < 64; ++t) {
        // prefetch next tile's B frags + e_sq (t=63 wraps to 0 — valid, unused)
        int fb = ((t + 1) & 63) * 128 + l;
        short8 nh0 = Bh[fb], nh1 = Bh[fb + 64];
        short8 nl0 = Bl[fb], nl1 = Bl[fb + 64];
        float esv_n = esq[((t + 1) & 63) * 16 + col];
        // pin: loads above may not sink below, MFMAs below may not hoist above.
        // This is the whole point of R9 — without it the compiler moves the
        // loads to the body bottom (R8: VGPR=52) and every tile eats L2 latency.
        __builtin_amdgcn_sched_barrier(0);

        f32x4 Ca = {esv_c, esv_c, esv_c, esv_c};
        f32x4 Cb = {esv_c, esv_c, esv_c, esv_c};
        // single chain per rowset; a/b chains independent -> ILP for the pipe
        Ca = __builtin_amdgcn_mfma_f32_16x16x32_bf16(Ah0a, bh0, Ca, 0, 0, 0);
        Cb = __builtin_amdgcn_mfma_f32_16x16x32_bf16(Ah0b, bh0, Cb, 0, 0, 0);
        Ca = __builtin_amdgcn_mfma_f32_16x16x32_bf16(Ah1a, bh1, Ca, 0, 0, 0);
        Cb = __builtin_amdgcn_mfma_f32_16x16x32_bf16(Ah1b, bh1, Cb, 0, 0, 0);
        Ca = __builtin_amdgcn_mfma_f32_16x16x32_bf16(Ah0a, bl0, Ca, 0, 0, 0);
        Cb = __builtin_amdgcn_mfma_f32_16x16x32_bf16(Ah0b, bl0, Cb, 0, 0, 0);
        Ca = __builtin_amdgcn_mfma_f32_16x16x32_bf16(Ah1a, bl1, Ca, 0, 0, 0);
        Cb = __builtin_amdgcn_mfma_f32_16x16x32_bf16(Ah1b, bl1, Cb, 0, 0, 0);
        Ca = __builtin_amdgcn_mfma_f32_16x16x32_bf16(Al0a, bh0, Ca, 0, 0, 0);
        Cb = __builtin_amdgcn_mfma_f32_16x16x32_bf16(Al0b, bh0, Cb, 0, 0, 0);
        Ca = __builtin_amdgcn_mfma_f32_16x16x32_bf16(Al1a, bh1, Ca, 0, 0, 0);
        Cb = __builtin_amdgcn_mfma_f32_16x16x32_bf16(Al1b, bh1, Cb, 0, 0, 0);

        int tc = t * 16;
        #pragma unroll
        for (int r = 0; r < 4; ++r) {
            float va = Ca[r];
            bool lta = va < besta[r];
            float mxa = fmaxf(va, besta[r]);
            besta[r] = fminf(va, besta[r]);
            seca[r]  = fminf(seca[r], mxa);
            bidxa[r] = lta ? tc : bidxa[r];
            float vb = Cb[r];
            bool ltb = vb < bestb[r];
            float mxb = fmaxf(vb, bestb[r]);
            bestb[r] = fminf(vb, bestb[r]);
            secb[r]  = fminf(secb[r], mxb);
            bidxb[r] = ltb ? tc : bidxb[r];
        }
        bh0 = nh0; bh1 = nh1; bl0 = nl0; bl1 = nl1;
        esv_c = esv_n;
    }

    // per-register reduce across the 16 col-lanes (masks 1..8 preserve quad)
    #pragma unroll
    for (int r = 0; r < 4; ++r) {
        {   // rowset a
            u64 b = ((u64)fmap(besta[r]) << 32) | (uint32_t)(bidxa[r] + col);
            u64 s = ((u64)fmap(seca[r]) << 32) | 0xFFFFFFFFu;
            #pragma unroll
            for (int m = 8; m >= 1; m >>= 1) {
                u64 ob = shfl_xor_u64(b, m);
                u64 os = shfl_xor_u64(s, m);
                top2_merge(b, s, ob, os);
            }
            if (col == 0) {
                int rowL = wid * 32 + quad * 4 + r;       // verified C row map
                bk[rowL] = (int)(uint32_t)(b & 0xFFFFFFFFu);
                float vb = funmap((uint32_t)(b >> 32));
                float vs = funmap((uint32_t)(s >> 32));
                if (vs - vb < TAU) {
                    int idx = atomicAdd(&flag_n, 1);
                    flag_list[idx] = rowL;
                }
            }
        }
        {   // rowset b
            u64 b = ((u64)fmap(bestb[r]) << 32) | (uint32_t)(bidxb[r] + col);
            u64 s = ((u64)fmap(secb[r]) << 32) | 0xFFFFFFFFu;
            #pragma unroll
            for (int m = 8; m >= 1; m >>= 1) {
                u64 ob = shfl_xor_u64(b, m);
                u64 os = shfl_xor_u64(s, m);
                top2_merge(b, s, ob, os);
            }
            if (col == 0) {
                int rowL = wid * 32 + 16 + quad * 4 + r;
                bk[rowL] = (int)(uint32_t)(b & 0xFFFFFFFFu);
                float vb = funmap((uint32_t)(b >> 32));
                float vs = funmap((uint32_t)(s >> 32));
                if (vs - vb < TAU) {
                    int idx = atomicAdd(&flag_n, 1);
                    flag_list[idx] = rowL;
                }
            }
        }
    }
    __syncthreads();

    // fused exact refine for flagged rows (rare: ~0.03 rows/block expected).
    // Identical math + tie-breaks to the proven vq_refine kernel:
    // ET[k*D+d] == E[d*K+k] exactly; fp64 fma over ascending d; v<best with
    // ascending k; wave reduce then cross-wave lowest-k-on-tie merge.
    {
        int nf = flag_n;                         // uniform across block
        for (int f = 0; f < nf; ++f) {
            int rowR = flag_list[f];
            if (t0 < D) xs64[t0] = (double)x[(size_t)(base + rowR) * D + t0];
            __syncthreads();
            double best = 1.0e300; int bestk = 0;
            #pragma unroll
            for (int j = 0; j < 4; ++j) {
                int k = t0 * 4 + j;
                const float* ep = ET + (size_t)k * D;
                double a = 0.0;
                #pragma unroll 4
                for (int d = 0; d < D; ++d)
                    a = fma(xs64[d], (double)ep[d], a);
                double v = fma(-2.0, a, e_sq64[k]);
                if (v < best) { best = v; bestk = k; }
            }
            #pragma unroll
            for (int m = 32; m >= 1; m >>= 1) {
                double ov = shfl_xor_f64(best, m);
                int    ok = __shfl_xor(bestk, m, 64);
                if (ov < best || (ov == best && ok < bestk)) { best = ov; bestk = ok; }
            }
            if ((t0 & 63) == 0) { wbv[t0 >> 6] = best; wbk_s[t0 >> 6] = bestk; }
            __syncthreads();
            if (t0 == 0) {
                double bv = wbv[0]; int bb = wbk_s[0];
                for (int w = 1; w < 4; ++w)
                    if (wbv[w] < bv || (wbv[w] == bv && wbk_s[w] < bb)) { bv = wbv[w]; bb = wbk_s[w]; }
                bk[rowR] = bb;
            }
            __syncthreads();
        }
    }

    // gather: thread t0 copies 128 B of its row from ET
    {
        int row = t0 >> 1, seg = t0 & 1;
        const float4* ep = (const float4*)(ET + (size_t)bk[row] * D + seg * 32);
        float4* op = (float4*)(out + (size_t)(base + row) * D + seg * 32);
        #pragma unroll
        for (int q = 0; q < 8; ++q) op[q] = ep[q];
    }
}

extern "C" void kernel_launch(void* const* d_in, const int* in_sizes, int n_in,
                              void* d_out, int out_size, void* d_ws, size_t ws_size,
                              hipStream_t stream) {
    const float* x = (const float*)d_in[0];
    const float* E = (const float*)d_in[1];
    float* out = (float*)d_out;
    int N = in_sizes[0] / D;   // 131072

    // ws: e_sq64 8K | e_sq32 4K | ET 256K | Bhi 128K | Blo 128K
    char* w = (char*)d_ws;
    double*         e_sq64 = (double*)w;          w += K * sizeof(double);
    float*          e_sq32 = (float*)w;           w += K * sizeof(float);
    float*          ET     = (float*)w;           w += (size_t)K * D * sizeof(float);
    unsigned short* Bhi    = (unsigned short*)w;  w += (size_t)K * D * sizeof(unsigned short);
    unsigned short* Blo    = (unsigned short*)w;  w += (size_t)K * D * sizeof(unsigned short);

    vq_prep<<<256, 256, 0, stream>>>(E, e_sq64, e_sq32, ET, Bhi, Blo);
    vq_screen<<<N / 128, 256, 0, stream>>>(x, (const short8*)Bhi, (const short8*)Blo,
                                           e_sq32, e_sq64, ET, out);
}